// Round 2
// baseline (363.210 us; speedup 1.0000x reference)
//
#include <hip/hip_runtime.h>

// Problem constants (fixed by the harness/reference)
#define NUM_B 4
#define QLEN 256
#define SEQ 2048
#define NH 32
#define NKVH 8
#define HD 128
#define PAGE 16
#define NPAGES 640
#define PPS 128              // pages (blocks) per sequence
#define KD (NKVH*HD)         // 1024 floats per cache slot
#define VOFF ((size_t)NPAGES*PAGE*KD)
#define KVB 64               // kv-tile length
#define QSCALE 0.08838834764831845f   // 1/sqrt(128)

typedef __attribute__((ext_vector_type(8))) short bhalf8;
typedef __attribute__((ext_vector_type(4))) float floatx4;

__device__ __forceinline__ unsigned short f2bf(float f){
  union { float f; unsigned u; } x; x.f = f;
  unsigned r = x.u + 0x7fffu + ((x.u >> 16) & 1u);   // RNE
  return (unsigned short)(r >> 16);
}

__device__ __forceinline__ bhalf8 pack8(const float* v){
  bhalf8 o;
  o[0]=(short)f2bf(v[0]); o[1]=(short)f2bf(v[1]);
  o[2]=(short)f2bf(v[2]); o[3]=(short)f2bf(v[3]);
  o[4]=(short)f2bf(v[4]); o[5]=(short)f2bf(v[5]);
  o[6]=(short)f2bf(v[6]); o[7]=(short)f2bf(v[7]);
  return o;
}

// Phase A: scatter new K/V tokens into the paged cache (in place).
__global__ void scatter_kv(const float* __restrict__ k, const float* __restrict__ v,
                           float* __restrict__ cache, const int* __restrict__ slots){
  int t = blockIdx.x, tid = threadIdx.x;     // t: token 0..1023, tid: 0..255
  int slot = slots[t];
  float4 kq = *(const float4*)(k + (size_t)t*KD + tid*4);
  float4 vq = *(const float4*)(v + (size_t)t*KD + tid*4);
  *(float4*)(cache + (size_t)slot*KD + tid*4) = kq;
  *(float4*)(cache + VOFF + (size_t)slot*KD + tid*4) = vq;
}

// Phase B: flash attention. Grid: 4(b) * 8(kvh) * 8(row-tile) = 256 blocks, 512 thr.
// Block handles 128 q-rows of one (b, kvh): rows = one GQA head's 128-query half.
__global__ __launch_bounds__(512)
void paged_attn(const float* __restrict__ qin, const float* __restrict__ cache,
                const int* __restrict__ btab, float* __restrict__ out){
  // K tile [s][d] bf16, swizzled: byte = s*256 + d*2 ^ ((s&7)<<4)
  __shared__ unsigned short Ks[KVB*HD];
  // V tile transposed [d][s] bf16, swizzled: byte = d*128 + s*2 ^ ((d&7)<<4)
  __shared__ unsigned short Vt[HD*KVB];
  // P per-wave [r][s] bf16, swizzled: byte = r*128 + s*2 ^ ((r&7)<<4)
  __shared__ unsigned short Ps[8*16*KVB];

  const int tid = threadIdx.x;
  const int w = tid>>6, l = tid&63, l16 = l&15, lg = l>>4;
  const int bid = blockIdx.x;
  const int b = bid>>6, kvh = (bid>>3)&7, rt = bid&7;
  const int qlo = (rt&1)<<7;                 // 0 or 128 within the 256 queries
  const int h = kvh*4 + (rt>>1);             // query head
  const int* bt = btab + b*PPS;

  // Q A-fragments (row = l&15, k = kc*32 + (l>>4)*8 + i), pre-scaled.
  bhalf8 aq[4];
  {
    int qi = qlo + w*16 + l16;
    const float* qp = qin + (size_t)(b*QLEN+qi)*(NH*HD) + h*HD;
    #pragma unroll
    for (int kc=0;kc<4;kc++){
      float4 f0 = *(const float4*)(qp + kc*32 + lg*8);
      float4 f1 = *(const float4*)(qp + kc*32 + lg*8 + 4);
      float tmp[8] = {f0.x*QSCALE,f0.y*QSCALE,f0.z*QSCALE,f0.w*QSCALE,
                      f1.x*QSCALE,f1.y*QSCALE,f1.z*QSCALE,f1.w*QSCALE};
      aq[kc] = pack8(tmp);
    }
  }

  float mrun[4], lrun[4]; floatx4 acc[8];
  #pragma unroll
  for (int r=0;r<4;r++){ mrun[r]=-1e30f; lrun[r]=0.f; }
  #pragma unroll
  for (int dt=0;dt<8;dt++) acc[dt] = floatx4{0.f,0.f,0.f,0.f};

  const int nt = (qlo==0)?30:32;             // tiles fully past causal limit skipped
  const int qpbase = SEQ - QLEN + qlo + w*16 + lg*4;  // +r = abs pos of D-layout row r

  for (int t=0;t<nt;t++){
    const int s0 = t*KVB;
    __syncthreads();                         // prev tile's LDS reads done

    // --- stage K: [s][d] bf16 swizzled; coalesced 512B/16-lane global reads ---
    #pragma unroll
    for (int it=0;it<2;it++){
      int c = tid + (it<<9);
      int dch = c&15, s = c>>4;
      int p = s0 + s;
      int slot = bt[p>>4]*PAGE + (p&15);
      const float* kp = cache + (size_t)slot*KD + kvh*HD + dch*8;
      float4 f0 = *(const float4*)kp;
      float4 f1 = *(const float4*)(kp+4);
      float tmp[8] = {f0.x,f0.y,f0.z,f0.w,f1.x,f1.y,f1.z,f1.w};
      int off = s*256 + dch*16; off ^= (s&7)<<4;
      *(bhalf8*)((char*)Ks + off) = pack8(tmp);
    }
    // --- stage V transposed: thread owns (d = tid&127, 8 s's); global reads are
    //     row-slices (lanes across d -> 256B coalesced), writes are b128 along s ---
    {
      int d = tid&127, sc = tid>>7;          // sc 0..3
      #pragma unroll
      for (int hf=0; hf<2; ++hf){
        int sb = hf*32 + sc*8;
        float tmp[8];
        #pragma unroll
        for (int i=0;i<8;i++){
          int p = s0 + sb + i;
          int slot = bt[p>>4]*PAGE + (p&15);
          tmp[i] = cache[VOFF + (size_t)slot*KD + kvh*HD + d];
        }
        int off = d*(KVB*2) + sb*2; off ^= (d&7)<<4;
        *(bhalf8*)((char*)Vt + off) = pack8(tmp);
      }
    }
    __syncthreads();

    // --- QK^T: S[st] (16q x 16s), A=Q frags, B=K^T from LDS ---
    floatx4 S[4];
    #pragma unroll
    for (int st=0;st<4;st++){
      S[st] = floatx4{0.f,0.f,0.f,0.f};
      int srow = st*16 + l16;
      #pragma unroll
      for (int kc=0;kc<4;kc++){
        int off = srow*256 + (kc*32+lg*8)*2; off ^= (srow&7)<<4;
        bhalf8 bk = *(bhalf8*)((char*)Ks + off);
        S[st] = __builtin_amdgcn_mfma_f32_16x16x32_bf16(aq[kc], bk, S[st], 0,0,0);
      }
    }

    // --- online softmax (rows are lane-local groups: row = lg*4 + r) ---
    float pe[4][4];      // [st][r]
    float alpha[4];
    const bool masked = (t >= nt-2);
    #pragma unroll
    for (int r=0;r<4;r++){
      float v0=S[0][r], v1=S[1][r], v2=S[2][r], v3=S[3][r];
      if (masked){
        int qp_ = qpbase + r;
        if (s0 +  0 + l16 > qp_) v0 = -1e30f;
        if (s0 + 16 + l16 > qp_) v1 = -1e30f;
        if (s0 + 32 + l16 > qp_) v2 = -1e30f;
        if (s0 + 48 + l16 > qp_) v3 = -1e30f;
      }
      float tm = fmaxf(fmaxf(v0,v1),fmaxf(v2,v3));
      #pragma unroll
      for (int dd=1; dd<16; dd<<=1) tm = fmaxf(tm, __shfl_xor(tm, dd));
      float mnew = fmaxf(mrun[r], tm);
      float al = __expf(mrun[r]-mnew);
      float e0=__expf(v0-mnew), e1=__expf(v1-mnew), e2=__expf(v2-mnew), e3=__expf(v3-mnew);
      pe[0][r]=e0; pe[1][r]=e1; pe[2][r]=e2; pe[3][r]=e3;
      float sm = e0+e1+e2+e3;
      #pragma unroll
      for (int dd=1; dd<16; dd<<=1) sm += __shfl_xor(sm, dd);
      lrun[r] = lrun[r]*al + sm;
      mrun[r] = mnew;
      alpha[r] = al;
    }
    #pragma unroll
    for (int dt=0;dt<8;dt++)
      #pragma unroll
      for (int r=0;r<4;r++) acc[dt][r] *= alpha[r];

    // --- P: C-layout -> LDS (bf16) -> A-layout fragments ---
    unsigned short* Pw = Ps + w*(16*KVB);
    #pragma unroll
    for (int st=0;st<4;st++)
      #pragma unroll
      for (int r=0;r<4;r++){
        int row = lg*4 + r;
        int off = row*(KVB*2) + (st*16+l16)*2; off ^= (row&7)<<4;
        *(unsigned short*)((char*)Pw + off) = f2bf(pe[st][r]);
      }
    bhalf8 pa[2];
    #pragma unroll
    for (int kk=0;kk<2;kk++){
      int off = l16*(KVB*2) + (kk*32+lg*8)*2; off ^= (l16&7)<<4;
      pa[kk] = *(bhalf8*)((char*)Pw + off);
    }
    // --- PV: acc += P x V, B = V^T-frag from transposed V tile ---
    #pragma unroll
    for (int dt=0;dt<8;dt++){
      #pragma unroll
      for (int kk=0;kk<2;kk++){
        int dr = dt*16 + l16;
        int off = dr*(KVB*2) + (kk*32+lg*8)*2; off ^= (dr&7)<<4;
        bhalf8 bv = *(bhalf8*)((char*)Vt + off);
        acc[dt] = __builtin_amdgcn_mfma_f32_16x16x32_bf16(pa[kk], bv, acc[dt], 0,0,0);
      }
    }
  }

  // epilogue: out[t][h*128+d] = acc / l
  #pragma unroll
  for (int dt=0;dt<8;dt++){
    #pragma unroll
    for (int r=0;r<4;r++){
      int qi = qlo + w*16 + lg*4 + r;
      out[(size_t)(b*QLEN+qi)*(NH*HD) + h*HD + dt*16 + l16] = acc[dt][r] / lrun[r];
    }
  }
}

extern "C" void kernel_launch(void* const* d_in, const int* in_sizes, int n_in,
                              void* d_out, int out_size, void* d_ws, size_t ws_size,
                              hipStream_t stream) {
  const float* q = (const float*)d_in[0];
  const float* k = (const float*)d_in[1];
  const float* v = (const float*)d_in[2];
  float*       cache = (float*)d_in[3];          // modified in place; harness restores
  const int*   slot_mapping = (const int*)d_in[4];
  const int*   block_tables = (const int*)d_in[5];
  float* out = (float*)d_out;

  scatter_kv<<<NUM_B*QLEN, 256, 0, stream>>>(k, v, cache, slot_mapping);
  paged_attn<<<NUM_B*NKVH*8, 512, 0, stream>>>(q, cache, block_tables, out);
}

// Round 3
// 254.213 us; speedup vs baseline: 1.4288x; 1.4288x over previous
//
#include <hip/hip_runtime.h>

// Problem constants (fixed by the harness/reference)
#define NUM_B 4
#define QLEN 256
#define SEQ 2048
#define NH 32
#define NKVH 8
#define HD 128
#define PAGE 16
#define NPAGES 640
#define PPS 128              // pages (blocks) per sequence
#define KD (NKVH*HD)         // 1024 floats per cache slot
#define VOFF ((size_t)NPAGES*PAGE*KD)
#define KVB 64               // kv-tile length
#define QSCALE 0.08838834764831845f   // 1/sqrt(128)

typedef __attribute__((ext_vector_type(8))) short bhalf8;
typedef __attribute__((ext_vector_type(4))) float floatx4;

__device__ __forceinline__ unsigned short f2bf(float f){
  union { float f; unsigned u; } x; x.f = f;
  unsigned r = x.u + 0x7fffu + ((x.u >> 16) & 1u);   // RNE
  return (unsigned short)(r >> 16);
}

__device__ __forceinline__ bhalf8 pack8(const float* v){
  bhalf8 o;
  o[0]=(short)f2bf(v[0]); o[1]=(short)f2bf(v[1]);
  o[2]=(short)f2bf(v[2]); o[3]=(short)f2bf(v[3]);
  o[4]=(short)f2bf(v[4]); o[5]=(short)f2bf(v[5]);
  o[6]=(short)f2bf(v[6]); o[7]=(short)f2bf(v[7]);
  return o;
}

// Phase A: scatter new K/V tokens into the paged cache (in place).
__global__ void scatter_kv(const float* __restrict__ k, const float* __restrict__ v,
                           float* __restrict__ cache, const int* __restrict__ slots){
  int t = blockIdx.x, tid = threadIdx.x;     // t: token 0..1023, tid: 0..255
  int slot = slots[t];
  float4 kq = *(const float4*)(k + (size_t)t*KD + tid*4);
  float4 vq = *(const float4*)(v + (size_t)t*KD + tid*4);
  *(float4*)(cache + (size_t)slot*KD + tid*4) = kq;
  *(float4*)(cache + VOFF + (size_t)slot*KD + tid*4) = vq;
}

// Phase B: flash attention, 2-phase pipelined (T3-minimum + T14 reg-staging).
// Grid: 4(b) * 8(kvh) * 8(rt) = 256 blocks, 512 thr. Block = 128 q-rows of one
// (b, query-head): rt = (head-in-group)*2 + q-half.
__global__ __launch_bounds__(512)
void paged_attn(const float* __restrict__ qin, const float* __restrict__ cache,
                const int* __restrict__ btab, float* __restrict__ out){
  // Double-buffered K [s][d] and V^T [d][s] bf16 tiles (XOR-swizzled), P per-wave.
  __shared__ unsigned short Ks[2*KVB*HD];    // 32 KB
  __shared__ unsigned short Vt[2*HD*KVB];    // 32 KB
  __shared__ unsigned short Ps[8*16*KVB];    // 16 KB
  __shared__ int slotT[PPS];                 // base slot (page*16) per page

  const int tid = threadIdx.x;
  const int w = tid>>6, l = tid&63, l16 = l&15, lg = l>>4;
  const int bid = blockIdx.x;
  const int b = bid>>6, kvh = (bid>>3)&7, rt = bid&7;
  const int qlo = (rt&1)<<7;                 // 0 or 128 within the 256 queries
  const int h = kvh*4 + (rt>>1);             // query head

  if (tid < PPS) slotT[tid] = btab[b*PPS + tid]*PAGE;

  // Q A-fragments (row = l&15, k = kc*32 + (l>>4)*8 + i), pre-scaled.
  bhalf8 aq[4];
  {
    int qi = qlo + w*16 + l16;
    const float* qp = qin + (size_t)(b*QLEN+qi)*(NH*HD) + h*HD;
    #pragma unroll
    for (int kc=0;kc<4;kc++){
      float4 f0 = *(const float4*)(qp + kc*32 + lg*8);
      float4 f1 = *(const float4*)(qp + kc*32 + lg*8 + 4);
      float tmp[8] = {f0.x*QSCALE,f0.y*QSCALE,f0.z*QSCALE,f0.w*QSCALE,
                      f1.x*QSCALE,f1.y*QSCALE,f1.z*QSCALE,f1.w*QSCALE};
      aq[kc] = pack8(tmp);
    }
  }
  __syncthreads();                           // slotT ready

  // --- reg-staging state (static names, no dynamic indexing: rule #20) ---
  float4 ka0,ka1,kb0,kb1;                    // K: 2 rows x 8 d per thread
  float va[8], vb[8];                        // V: 2 column-chunks of 8 s per thread
  const int dchK = tid&15, sA = tid>>4;      // K staging coords (sA 0..31)
  const int dV = tid&127, scV = tid>>7;      // V staging coords

  auto LOAD = [&](int t){                    // issue global loads for tile t
    const int s0 = t*KVB;
    int pA = s0 + sA, pB = pA + 32;
    int slA = slotT[pA>>4] + (pA&15);
    int slB = slotT[pB>>4] + (pB&15);
    const float4* kpA = (const float4*)(cache + (size_t)slA*KD + kvh*HD + dchK*8);
    const float4* kpB = (const float4*)(cache + (size_t)slB*KD + kvh*HD + dchK*8);
    ka0 = kpA[0]; ka1 = kpA[1]; kb0 = kpB[0]; kb1 = kpB[1];
    int sb0 = scV*8, sb1 = sb0 + 32;         // sb&15 in {0,8}: 8-s run stays in page
    const float* vp0 = cache + VOFF + (size_t)(slotT[(s0+sb0)>>4] + (sb0&15))*KD + kvh*HD + dV;
    const float* vp1 = cache + VOFF + (size_t)(slotT[(s0+sb1)>>4] + (sb1&15))*KD + kvh*HD + dV;
    #pragma unroll
    for (int i=0;i<8;i++){ va[i] = vp0[(size_t)i*KD]; vb[i] = vp1[(size_t)i*KD]; }
  };

  auto WRITE = [&](int buf){                 // convert + ds_write staged tile
    unsigned short* K_ = Ks + buf*(KVB*HD);
    unsigned short* V_ = Vt + buf*(HD*KVB);
    {
      float t0[8]={ka0.x,ka0.y,ka0.z,ka0.w,ka1.x,ka1.y,ka1.z,ka1.w};
      int off0 = sA*256 + dchK*16; off0 ^= (sA&7)<<4;
      *(bhalf8*)((char*)K_ + off0) = pack8(t0);
      float t1[8]={kb0.x,kb0.y,kb0.z,kb0.w,kb1.x,kb1.y,kb1.z,kb1.w};
      int sB = sA + 32;
      int off1 = sB*256 + dchK*16; off1 ^= (sB&7)<<4;
      *(bhalf8*)((char*)K_ + off1) = pack8(t1);
    }
    {
      int sb0 = scV*8, sb1 = sb0 + 32;
      int off0 = dV*(KVB*2) + sb0*2; off0 ^= (dV&7)<<4;
      *(bhalf8*)((char*)V_ + off0) = pack8(va);
      int off1 = dV*(KVB*2) + sb1*2; off1 ^= (dV&7)<<4;
      *(bhalf8*)((char*)V_ + off1) = pack8(vb);
    }
  };

  float mrun[4], lrun[4]; floatx4 acc[8];
  #pragma unroll
  for (int r=0;r<4;r++){ mrun[r]=-1e30f; lrun[r]=0.f; }
  #pragma unroll
  for (int dt=0;dt<8;dt++) acc[dt] = floatx4{0.f,0.f,0.f,0.f};

  const int nt = (qlo==0)?30:32;             // tiles fully past causal limit skipped
  const int qpbase = SEQ - QLEN + qlo + w*16 + lg*4;  // +r = abs pos of D-layout row r
  unsigned short* Pw = Ps + w*(16*KVB);

  // prologue: stage tile 0
  LOAD(0); WRITE(0);
  __syncthreads();
  int cur = 0;

  for (int t=0;t<nt;t++){
    const int s0 = t*KVB;
    const bool pre = (t+1 < nt);
    if (pre) LOAD(t+1);                      // loads fly under this tile's compute
    const unsigned short* K_ = Ks + cur*(KVB*HD);
    const unsigned short* V_ = Vt + cur*(HD*KVB);

    // --- QK^T: S[st] (16q x 16s), A=Q frags, B=K^T from LDS ---
    floatx4 S[4];
    #pragma unroll
    for (int st=0;st<4;st++){
      S[st] = floatx4{0.f,0.f,0.f,0.f};
      int srow = st*16 + l16;
      #pragma unroll
      for (int kc=0;kc<4;kc++){
        int off = srow*256 + (kc*32+lg*8)*2; off ^= (srow&7)<<4;
        bhalf8 bk = *(bhalf8*)((char*)K_ + off);
        S[st] = __builtin_amdgcn_mfma_f32_16x16x32_bf16(aq[kc], bk, S[st], 0,0,0);
      }
    }

    // --- online softmax (rows are lane-local groups: row = lg*4 + r) ---
    float pe[4][4];      // [st][r]
    float alpha[4];
    const bool masked = (t >= nt-2);
    #pragma unroll
    for (int r=0;r<4;r++){
      float v0=S[0][r], v1=S[1][r], v2=S[2][r], v3=S[3][r];
      if (masked){
        int qp_ = qpbase + r;
        if (s0 +  0 + l16 > qp_) v0 = -1e30f;
        if (s0 + 16 + l16 > qp_) v1 = -1e30f;
        if (s0 + 32 + l16 > qp_) v2 = -1e30f;
        if (s0 + 48 + l16 > qp_) v3 = -1e30f;
      }
      float tm = fmaxf(fmaxf(v0,v1),fmaxf(v2,v3));
      #pragma unroll
      for (int dd=1; dd<16; dd<<=1) tm = fmaxf(tm, __shfl_xor(tm, dd));
      float mnew = fmaxf(mrun[r], tm);
      float al = __expf(mrun[r]-mnew);
      float e0=__expf(v0-mnew), e1=__expf(v1-mnew), e2=__expf(v2-mnew), e3=__expf(v3-mnew);
      pe[0][r]=e0; pe[1][r]=e1; pe[2][r]=e2; pe[3][r]=e3;
      float sm = e0+e1+e2+e3;
      #pragma unroll
      for (int dd=1; dd<16; dd<<=1) sm += __shfl_xor(sm, dd);
      lrun[r] = lrun[r]*al + sm;
      mrun[r] = mnew;
      alpha[r] = al;
    }
    // T13-style guard: skip rescale when no row saw a new max (alpha==1 exact)
    bool needr = (alpha[0]<1.f)|(alpha[1]<1.f)|(alpha[2]<1.f)|(alpha[3]<1.f);
    if (__any(needr)){
      #pragma unroll
      for (int dt=0;dt<8;dt++)
        #pragma unroll
        for (int r=0;r<4;r++) acc[dt][r] *= alpha[r];
    }

    // --- P: C-layout -> LDS (bf16) -> A-layout fragments (per-wave buffer) ---
    #pragma unroll
    for (int st=0;st<4;st++)
      #pragma unroll
      for (int r=0;r<4;r++){
        int row = lg*4 + r;
        int off = row*(KVB*2) + (st*16+l16)*2; off ^= (row&7)<<4;
        *(unsigned short*)((char*)Pw + off) = f2bf(pe[st][r]);
      }
    bhalf8 pa[2];
    #pragma unroll
    for (int kk=0;kk<2;kk++){
      int off = l16*(KVB*2) + (kk*32+lg*8)*2; off ^= (l16&7)<<4;
      pa[kk] = *(bhalf8*)((char*)Pw + off);
    }
    // --- PV: acc += P x V, B = V^T-frag from transposed V tile ---
    #pragma unroll
    for (int dt=0;dt<8;dt++){
      #pragma unroll
      for (int kk=0;kk<2;kk++){
        int dr = dt*16 + l16;
        int off = dr*(KVB*2) + (kk*32+lg*8)*2; off ^= (dr&7)<<4;
        bhalf8 bv = *(bhalf8*)((char*)V_ + off);
        acc[dt] = __builtin_amdgcn_mfma_f32_16x16x32_bf16(pa[kk], bv, acc[dt], 0,0,0);
      }
    }

    if (pre){
      WRITE(cur^1);                          // vmcnt waits land here, after compute
      __syncthreads();                       // one barrier per tile
    }
    cur ^= 1;
  }

  // epilogue: out[t][h*128+d] = acc / l
  #pragma unroll
  for (int dt=0;dt<8;dt++){
    #pragma unroll
    for (int r=0;r<4;r++){
      int qi = qlo + w*16 + lg*4 + r;
      out[(size_t)(b*QLEN+qi)*(NH*HD) + h*HD + dt*16 + l16] = acc[dt][r] / lrun[r];
    }
  }
}

extern "C" void kernel_launch(void* const* d_in, const int* in_sizes, int n_in,
                              void* d_out, int out_size, void* d_ws, size_t ws_size,
                              hipStream_t stream) {
  const float* q = (const float*)d_in[0];
  const float* k = (const float*)d_in[1];
  const float* v = (const float*)d_in[2];
  float*       cache = (float*)d_in[3];          // modified in place; harness restores
  const int*   slot_mapping = (const int*)d_in[4];
  const int*   block_tables = (const int*)d_in[5];
  float* out = (float*)d_out;

  scatter_kv<<<NUM_B*QLEN, 256, 0, stream>>>(k, v, cache, slot_mapping);
  paged_attn<<<NUM_B*NKVH*8, 512, 0, stream>>>(q, cache, block_tables, out);
}